// Round 12
// baseline (113.681 us; speedup 1.0000x reference)
//
#include <hip/hip_runtime.h>

namespace {

constexpr int NQ = 12;
constexpr int THREADS = 256;

struct c32 { float r, i; };

__device__ __forceinline__ c32 cmul(c32 a, c32 b) {
    return { fmaf(a.r, b.r, -(a.i * b.i)), fmaf(a.r, b.i, a.i * b.r) };
}

// real-coefficient RY butterfly: (x,y) <- (cb*x - sb*y, sb*x + cb*y), 8 ops/pair
__device__ __forceinline__ void bfy(c32& x, c32& y, float cb, float sb) {
    const c32 a = x, b = y;
    x.r = fmaf(cb, a.r, -(sb * b.r));
    x.i = fmaf(cb, a.i, -(sb * b.i));
    y.r = fmaf(sb, a.r, cb * b.r);
    y.i = fmaf(sb, a.i, cb * b.i);
}

template<int BP>
__device__ __forceinline__ void applyRY(c32 v[16], float cb, float sb) {
    #pragma unroll
    for (int mi = 0; mi < 8; ++mi) {
        const int i0 = ((mi >> BP) << (BP + 1)) | (mi & ((1 << BP) - 1));
        bfy(v[i0], v[i0 | (1 << BP)], cb, sb);
    }
}

// ---- XOR-linear address algebra (identical to the 90.6us R5/R10 kernels) ----
__host__ __device__ constexpr int G(int t, int k) {
    for (int i = 0; i < k; ++i) t = (t ^ (t >> 1)) & 0xFFF;
    return t;
}
__host__ __device__ constexpr int Cm(int t) {
    int lo = 0;
    if (t & 0x010) lo ^= 0x2;
    if (t & 0x020) lo ^= 0x4;
    if (t & 0x040) lo ^= 0x8;
    if (t & 0x080) lo ^= 0x6;
    if (t & 0x100) lo ^= 0xA;
    if (t & 0x200) lo ^= 0xC;
    return t ^ lo;
}

// per-thread diag product tree for layer 0 (identical to R5/R10)
__device__ __forceinline__ void diagTree(c32 T[16], c32 C,
                                         const c32 pf0[4], const c32 pf1[4],
                                         const c32 qv[4], int sigma) {
    const c32 one = { 1.f, 0.f };
    T[0] = C;
    #pragma unroll
    for (int m = 3; m >= 0; --m) {
        const c32 qs0 = sigma ? qv[m] : one;
        const c32 qs1 = sigma ? one : qv[m];
        const c32 g00 = cmul(pf0[m], qs0);
        const c32 g01 = cmul(pf0[m], qs1);
        const c32 g10 = cmul(pf1[m], qs0);
        const c32 g11 = cmul(pf1[m], qs1);
        #pragma unroll
        for (int e = (1 << (3 - m)) - 1; e >= 0; --e) {
            const int j0 = e << (m + 1);
            const int sfxhi = __popc(e) & 1;
            const c32 ga = sfxhi ? g01 : g00;
            const c32 gb = sfxhi ? g10 : g11;
            T[j0 | (1 << m)] = cmul(T[j0], gb);
            T[j0]            = cmul(T[j0], ga);
        }
    }
}

__global__ __launch_bounds__(THREADS, 2)
void qcirc_kernel(const float* __restrict__ x, const float* __restrict__ thetas,
                  float* __restrict__ out) {
    // 2 batch elements per block: amp4[t] = { e0.re, e0.im, e1.re, e1.im }
    __shared__ alignas(16) float4 amp4[4096];    // 64 KB
    __shared__ float4 Vs[2][96];                 // per elem, per gate: (cb,sb,p0),(p1,q1)
    __shared__ float2 TbS[2][2][2][16];          // [e][K-1][sigma][j]
    __shared__ float2 CHiS[2][2][16];            // [e][K-1][h]
    __shared__ float2 CLoS[2][2][2][16];         // [e][K-1][sh][lo]
    __shared__ float red[2][4];

    const int tid = threadIdx.x;
    const int blk = blockIdx.x;

    // ---- gate build: threads 0..95 (e = tid/48), V = RX RZ RX RZfm RYfm -> P*Ry*Q ----
    if (tid < 96) {
        const int e = tid >= 48;
        const int g = tid - 48 * e;
        const float xv = x[2 * blk + e];
        const float x1 = asinf(xv);
        const float x2 = acosf(xv * xv);
        const float cy = cosf(0.5f * x1), sy = sinf(0.5f * x1);
        const float cz = cosf(0.5f * x2), sz = sinf(0.5f * x2);
        const c32 M00 = {  cz * cy, -sz * cy };
        const c32 M01 = { -cz * sy,  sz * sy };
        const c32 M10 = {  cz * sy,  sz * sy };
        const c32 M11 = {  cz * cy,  sz * cy };

        const float* th = thetas + g * 3;
        const float h0 = 0.5f * th[0], h1 = 0.5f * th[1], h2 = 0.5f * th[2];
        const float c0 = cosf(h0), s0 = sinf(h0);
        const float c1 = cosf(h1), s1 = sinf(h1);
        const float c2 = cosf(h2), s2 = sinf(h2);
        const c32 z0 = { c1, -s1 }, z1 = { c1, s1 };
        const c32 X00 = { c0, 0.f }, X01 = { 0.f, -s0 };
        const c32 A00 = cmul(z0, X00), A01 = cmul(z0, X01);
        const c32 A10 = cmul(z1, X01), A11 = cmul(z1, X00);
        const c32 Y00 = { c2, 0.f }, Y01 = { 0.f, -s2 };
        const c32 U00 = { Y00.r*A00.r - Y00.i*A00.i + Y01.r*A10.r - Y01.i*A10.i,
                          Y00.r*A00.i + Y00.i*A00.r + Y01.r*A10.i + Y01.i*A10.r };
        const c32 U01 = { Y00.r*A01.r - Y00.i*A01.i + Y01.r*A11.r - Y01.i*A11.i,
                          Y00.r*A01.i + Y00.i*A01.r + Y01.r*A11.i + Y01.i*A11.r };
        const c32 U10 = { Y01.r*A00.r - Y01.i*A00.i + Y00.r*A10.r - Y00.i*A10.i,
                          Y01.r*A00.i + Y01.i*A00.r + Y00.r*A10.i + Y00.i*A10.r };
        const c32 U11 = { Y01.r*A01.r - Y01.i*A01.i + Y00.r*A11.r - Y00.i*A11.i,
                          Y01.r*A01.i + Y01.i*A01.r + Y00.r*A11.i + Y00.i*A11.r };
        const c32 V00 = { U00.r*M00.r - U00.i*M00.i + U01.r*M10.r - U01.i*M10.i,
                          U00.r*M00.i + U00.i*M00.r + U01.r*M10.i + U01.i*M10.r };
        const c32 V01 = { U00.r*M01.r - U00.i*M01.i + U01.r*M11.r - U01.i*M11.i,
                          U00.r*M01.i + U00.i*M01.r + U01.r*M11.i + U01.i*M11.r };
        const c32 V10 = { U10.r*M00.r - U10.i*M00.i + U11.r*M10.r - U11.i*M10.i,
                          U10.r*M00.i + U10.i*M00.r + U11.r*M10.i + U11.i*M10.r };
        const c32 V11 = { U10.r*M01.r - U10.i*M01.i + U11.r*M11.r - U11.i*M11.i,
                          U10.r*M01.i + U10.i*M01.r + U11.r*M11.i + U11.i*M11.r };

        float cb = sqrtf(V00.r*V00.r + V00.i*V00.i);
        float sb = sqrtf(V10.r*V10.r + V10.i*V10.i);
        c32 p0, p1, q1;
        const float eps = 1e-6f;
        if (sb <= eps) {
            const float icb = 1.f / cb;
            p0 = { V00.r*icb, V00.i*icb };
            p1 = { V11.r*icb, V11.i*icb };
            q1 = { 1.f, 0.f };
            cb = 1.f; sb = 0.f;
        } else if (cb <= eps) {
            const float isb = 1.f / sb;
            p1 = { V10.r*isb, V10.i*isb };
            p0 = { -V01.r*isb, -V01.i*isb };
            q1 = { 1.f, 0.f };
            cb = 0.f; sb = 1.f;
        } else {
            const float icb = 1.f / cb, isb = 1.f / sb;
            p0 = { V00.r*icb, V00.i*icb };
            p1 = { V10.r*isb, V10.i*isb };
            const c32 t = { V11.r*p1.r + V11.i*p1.i, V11.i*p1.r - V11.r*p1.i };
            q1 = { t.r*icb, t.i*icb };
        }
        Vs[e][g * 2]     = make_float4(cb, sb, p0.r, p0.i);
        Vs[e][g * 2 + 1] = make_float4(p1.r, p1.i, q1.r, q1.i);
    }
    __syncthreads();

    // ---- boundary diag tables per element (vid mirrors the R10 tid roles) ----
    #define BUILD_TABLES(E, VID)                                                     \
    {                                                                                \
        const int vid = (VID);                                                       \
        if (vid < 64) {                                                              \
            const int bK = (vid >> 5) + 1;                                           \
            const int sg = (vid >> 4) & 1;                                           \
            const int j  = vid & 15;                                                 \
            c32 acc = { 1.f, 0.f };                                                  \
            _Pragma("unroll")                                                        \
            for (int m = 3; m >= 0; --m) {                                           \
                const int Q = 11 - m;                                                \
                const float4 s0 = Vs[E][(bK*NQ+Q)*2];                                \
                const float4 s1 = Vs[E][(bK*NQ+Q)*2+1];                              \
                const float4 n1 = Vs[E][((bK+1)*NQ+Q)*2+1];                          \
                const c32 pf = ((j >> m) & 1) ? c32{ s1.x, s1.y } : c32{ s0.z, s0.w }; \
                acc = cmul(acc, pf);                                                 \
                if (sg ^ (__popc(j >> m) & 1)) acc = cmul(acc, c32{ n1.z, n1.w });   \
            }                                                                        \
            TbS[E][bK-1][sg][j] = make_float2(acc.r, acc.i);                         \
        } else if (vid < 96) {                                                       \
            const int idx = vid - 64;                                               \
            const int bK = (idx >> 4) + 1;                                           \
            const int h  = idx & 15;                                                 \
            c32 acc = { 1.f, 0.f };                                                  \
            _Pragma("unroll")                                                        \
            for (int Q = 0; Q < 4; ++Q) {                                            \
                const float4 s0 = Vs[E][(bK*NQ+Q)*2];                                \
                const float4 s1 = Vs[E][(bK*NQ+Q)*2+1];                              \
                const float4 n1 = Vs[E][((bK+1)*NQ+Q)*2+1];                          \
                const c32 pf = ((h >> (3-Q)) & 1) ? c32{ s1.x, s1.y } : c32{ s0.z, s0.w }; \
                acc = cmul(acc, pf);                                                 \
                if (__popc(h >> (3-Q)) & 1) acc = cmul(acc, c32{ n1.z, n1.w });      \
            }                                                                        \
            CHiS[E][bK-1][h] = make_float2(acc.r, acc.i);                            \
        } else if (vid < 160) {                                                      \
            const int idx = vid - 96;                                               \
            const int bK = (idx >> 5) + 1;                                           \
            const int sh = (idx >> 4) & 1;                                           \
            const int lo = idx & 15;                                                 \
            c32 acc = { 1.f, 0.f };                                                  \
            _Pragma("unroll")                                                        \
            for (int Q = 4; Q < 8; ++Q) {                                            \
                const float4 s0 = Vs[E][(bK*NQ+Q)*2];                                \
                const float4 s1 = Vs[E][(bK*NQ+Q)*2+1];                              \
                const float4 n1 = Vs[E][((bK+1)*NQ+Q)*2+1];                          \
                const c32 pf = ((lo >> (7-Q)) & 1) ? c32{ s1.x, s1.y } : c32{ s0.z, s0.w }; \
                acc = cmul(acc, pf);                                                 \
                if (sh ^ (__popc(lo >> (7-Q)) & 1)) acc = cmul(acc, c32{ n1.z, n1.w }); \
            }                                                                        \
            CLoS[E][bK-1][sh][lo] = make_float2(acc.r, acc.i);                       \
        }                                                                            \
    }

    if (tid < 160) BUILD_TABLES(0, tid)
    if (tid >= 96) BUILD_TABLES(1, tid - 96)
    #undef BUILD_TABLES

    // ---- layer 0: tensor product per element (Q(1) folded), write b128 pairs ----
    {
        const int sg0 = __popc(tid) & 1;
        c32 T0[16], T1[16];
        #pragma unroll
        for (int e = 0; e < 2; ++e) {
            c32 C = { 1.f, 0.f };
            #pragma unroll
            for (int q = 0; q < 8; ++q) {
                const float4 s0 = Vs[e][q*2];
                const float4 s1 = Vs[e][q*2+1];
                const bool bit = (tid >> (7 - q)) & 1;
                const c32 ee = bit ? c32{ s1.x * s0.y, s1.y * s0.y }
                                  : c32{ s0.z * s0.x, s0.w * s0.x };
                C = cmul(C, ee);
                const float4 n1 = Vs[e][(NQ+q)*2+1];
                if (__popc(tid >> (7 - q)) & 1) C = cmul(C, c32{ n1.z, n1.w });
            }
            c32 pf0[4], pf1[4], qv[4];
            #pragma unroll
            for (int m = 0; m < 4; ++m) {
                const int Q = 11 - m;
                const float4 s0 = Vs[e][Q*2];
                const float4 s1 = Vs[e][Q*2+1];
                const float4 n1 = Vs[e][(NQ+Q)*2+1];
                pf0[m] = { s0.z * s0.x, s0.w * s0.x };
                pf1[m] = { s1.x * s0.y, s1.y * s0.y };
                qv[m]  = { n1.z, n1.w };
            }
            diagTree(e == 0 ? T0 : T1, C, pf0, pf1, qv, sg0);
        }
        const int beta = Cm(tid << 4);
        #pragma unroll
        for (int j = 0; j < 16; ++j)
            amp4[beta ^ j] = make_float4(T0[j].r, T0[j].i, T1[j].r, T1[j].i);
    }
    __syncthreads();

    // ---- layers 1..3: dual-element RY passes; diag at pass 2; layer-3 fused readout ----
    const int Lo = tid & 15, Hh = tid >> 4;
    float accA = 0.f, accB = 0.f;

    #define PASS_CORE(K, SH, BASEEXPR, Q0)                                           \
        const float4 A0 = Vs[0][((K)*NQ+(Q0))*2],   A1 = Vs[0][((K)*NQ+(Q0)+1)*2];   \
        const float4 A2 = Vs[0][((K)*NQ+(Q0)+2)*2], A3 = Vs[0][((K)*NQ+(Q0)+3)*2];   \
        const float4 B0 = Vs[1][((K)*NQ+(Q0))*2],   B1 = Vs[1][((K)*NQ+(Q0)+1)*2];   \
        const float4 B2 = Vs[1][((K)*NQ+(Q0)+2)*2], B3 = Vs[1][((K)*NQ+(Q0)+3)*2];   \
        const int base = Cm(G((BASEEXPR), (K)));                                     \
        c32 vA[16], vB[16];                                                          \
        _Pragma("unroll")                                                            \
        for (int j = 0; j < 16; ++j) {                                               \
            const float4 F = amp4[base ^ Cm(G(j << (SH), (K)))];                     \
            vA[j] = { F.x, F.y }; vB[j] = { F.z, F.w };                              \
        }                                                                            \
        applyRY<3>(vA, A0.x, A0.y); applyRY<2>(vA, A1.x, A1.y);                      \
        applyRY<1>(vA, A2.x, A2.y); applyRY<0>(vA, A3.x, A3.y);                      \
        applyRY<3>(vB, B0.x, B0.y); applyRY<2>(vB, B1.x, B1.y);                      \
        applyRY<1>(vB, B2.x, B2.y); applyRY<0>(vB, B3.x, B3.y);

    #define PASS_STORE(K, SH)                                                        \
        _Pragma("unroll")                                                            \
        for (int j = 0; j < 16; ++j)                                                 \
            amp4[base ^ Cm(G(j << (SH), (K)))] =                                     \
                make_float4(vA[j].r, vA[j].i, vB[j].r, vB[j].i);                     \
        __syncthreads();

    #define RUN_PASS_PLAIN(K, SH, BASEEXPR, Q0)                                      \
    {                                                                                \
        PASS_CORE(K, SH, BASEEXPR, Q0)                                               \
        PASS_STORE(K, SH)                                                            \
    }

    #define RUN_PASS_DIAG(K)                                                         \
    {                                                                                \
        PASS_CORE(K, 0, (Hh << 8) | (Lo << 4), 8)                                    \
        const int sgm = __popc(tid) & 1;                                             \
        const int sgh = __popc(tid >> 4) & 1;                                        \
        {                                                                            \
            const float2 ch = CHiS[0][K-1][Hh];                                      \
            const float2 cl = CLoS[0][K-1][sgh][Lo];                                 \
            const c32 CT = cmul(c32{ch.x,ch.y}, c32{cl.x,cl.y});                     \
            _Pragma("unroll")                                                        \
            for (int j = 0; j < 16; ++j) {                                           \
                const float2 tb = TbS[0][K-1][sgm][j];                               \
                vA[j] = cmul(vA[j], cmul(CT, c32{tb.x, tb.y}));                      \
            }                                                                        \
        }                                                                            \
        {                                                                            \
            const float2 ch = CHiS[1][K-1][Hh];                                      \
            const float2 cl = CLoS[1][K-1][sgh][Lo];                                 \
            const c32 CT = cmul(c32{ch.x,ch.y}, c32{cl.x,cl.y});                     \
            _Pragma("unroll")                                                        \
            for (int j = 0; j < 16; ++j) {                                           \
                const float2 tb = TbS[1][K-1][sgm][j];                               \
                vB[j] = cmul(vB[j], cmul(CT, c32{tb.x, tb.y}));                      \
            }                                                                        \
        }                                                                            \
        PASS_STORE(K, 0)                                                             \
    }

    #define RUN_PASS_OUT(K)                                                          \
    {                                                                                \
        PASS_CORE(K, 0, (Hh << 8) | (Lo << 4), 8)                                    \
        const int sgnHL = (__popc(Hh & 5) ^ __popc(Lo & 5)) & 1;                     \
        _Pragma("unroll")                                                            \
        for (int j = 0; j < 16; ++j) {                                               \
            const float mA = fmaf(vA[j].r, vA[j].r, vA[j].i * vA[j].i);              \
            const float mB = fmaf(vB[j].r, vB[j].r, vB[j].i * vB[j].i);              \
            if ((sgnHL ^ __popc(j & 5)) & 1) { accA -= mA; accB -= mB; }             \
            else                             { accA += mA; accB += mB; }             \
        }                                                                            \
    }

    RUN_PASS_PLAIN(1, 8, tid, 0)
    RUN_PASS_PLAIN(1, 4, (Hh << 8) | Lo, 4)
    RUN_PASS_DIAG(1)
    RUN_PASS_PLAIN(2, 8, tid, 0)
    RUN_PASS_PLAIN(2, 4, (Hh << 8) | Lo, 4)
    RUN_PASS_DIAG(2)
    RUN_PASS_PLAIN(3, 8, tid, 0)
    RUN_PASS_PLAIN(3, 4, (Hh << 8) | Lo, 4)
    RUN_PASS_OUT(3)

    #undef RUN_PASS_PLAIN
    #undef RUN_PASS_DIAG
    #undef RUN_PASS_OUT
    #undef PASS_CORE
    #undef PASS_STORE

    // ---- reduce: two independent sums ----
    #pragma unroll
    for (int off = 32; off > 0; off >>= 1) {
        accA += __shfl_down(accA, off, 64);
        accB += __shfl_down(accB, off, 64);
    }
    if ((tid & 63) == 0) { red[0][tid >> 6] = accA; red[1][tid >> 6] = accB; }
    __syncthreads();
    if (tid == 0) {
        out[2 * blk]     = red[0][0] + red[0][1] + red[0][2] + red[0][3];
        out[2 * blk + 1] = red[1][0] + red[1][1] + red[1][2] + red[1][3];
    }
}

} // namespace

extern "C" void kernel_launch(void* const* d_in, const int* in_sizes, int n_in,
                              void* d_out, int out_size, void* d_ws, size_t ws_size,
                              hipStream_t stream) {
    const float* x      = (const float*)d_in[0];
    const float* thetas = (const float*)d_in[1];
    float* out          = (float*)d_out;
    const int batch = in_sizes[0];
    qcirc_kernel<<<batch / 2, THREADS, 0, stream>>>(x, thetas, out);
}

// Round 13
// 89.962 us; speedup vs baseline: 1.2636x; 1.2636x over previous
//
#include <hip/hip_runtime.h>

namespace {

constexpr int NQ = 12;
constexpr int DIM = 1 << NQ;   // 4096
constexpr int THREADS = 256;

struct c32 { float r, i; };

__device__ __forceinline__ c32 cmul(c32 a, c32 b) {
    return { fmaf(a.r, b.r, -(a.i * b.i)), fmaf(a.r, b.i, a.i * b.r) };
}

// real-coefficient RY butterfly: (x,y) <- (cb*x - sb*y, sb*x + cb*y), 8 ops/pair
__device__ __forceinline__ void bfy(c32& x, c32& y, float cb, float sb) {
    const c32 a = x, b = y;
    x.r = fmaf(cb, a.r, -(sb * b.r));
    x.i = fmaf(cb, a.i, -(sb * b.i));
    y.r = fmaf(sb, a.r, cb * b.r);
    y.i = fmaf(sb, a.i, cb * b.i);
}

template<int BP>
__device__ __forceinline__ void applyRY(c32 v[16], float cb, float sb) {
    #pragma unroll
    for (int mi = 0; mi < 8; ++mi) {
        const int i0 = ((mi >> BP) << (BP + 1)) | (mi & ((1 << BP) - 1));
        bfy(v[i0], v[i0 | (1 << BP)], cb, sb);
    }
}

// intra-wave LDS RAW fence: drain own wave's ds ops, no cross-wave barrier.
// Safe for the pass1->pass2 exchange: reader set == writer set per quarter-wave.
__device__ __forceinline__ void wave_lds_fence() {
    asm volatile("s_waitcnt lgkmcnt(0)" ::: "memory");
}

// ---- XOR-linear address algebra (identical to the 90.6us R5/R10 kernels) ----
__host__ __device__ constexpr int G(int t, int k) {
    for (int i = 0; i < k; ++i) t = (t ^ (t >> 1)) & 0xFFF;
    return t;
}
__host__ __device__ constexpr int Cm(int t) {
    int lo = 0;
    if (t & 0x010) lo ^= 0x2;
    if (t & 0x020) lo ^= 0x4;
    if (t & 0x040) lo ^= 0x8;
    if (t & 0x080) lo ^= 0x6;
    if (t & 0x100) lo ^= 0xA;
    if (t & 0x200) lo ^= 0xC;
    return t ^ lo;
}

// per-thread diag product tree for layer 0 (identical to R5/R10)
__device__ __forceinline__ void diagTree(c32 T[16], c32 C,
                                         const c32 pf0[4], const c32 pf1[4],
                                         const c32 qv[4], int sigma) {
    const c32 one = { 1.f, 0.f };
    T[0] = C;
    #pragma unroll
    for (int m = 3; m >= 0; --m) {
        const c32 qs0 = sigma ? qv[m] : one;
        const c32 qs1 = sigma ? one : qv[m];
        const c32 g00 = cmul(pf0[m], qs0);
        const c32 g01 = cmul(pf0[m], qs1);
        const c32 g10 = cmul(pf1[m], qs0);
        const c32 g11 = cmul(pf1[m], qs1);
        #pragma unroll
        for (int e = (1 << (3 - m)) - 1; e >= 0; --e) {
            const int j0 = e << (m + 1);
            const int sfxhi = __popc(e) & 1;
            const c32 ga = sfxhi ? g01 : g00;
            const c32 gb = sfxhi ? g10 : g11;
            T[j0 | (1 << m)] = cmul(T[j0], gb);
            T[j0]            = cmul(T[j0], ga);
        }
    }
}

__global__ __launch_bounds__(THREADS)
void qcirc_kernel(const float* __restrict__ x, const float* __restrict__ thetas,
                  float* __restrict__ out) {
    __shared__ alignas(16) float2 amp[DIM];   // 32 KB state, layout Cm(G(t,l))
    __shared__ float4 Vs[4 * NQ * 2];         // per gate: (cb,sb,p0r,p0i),(p1r,p1i,q1r,q1i)
    __shared__ float2 TbS[2][2][16];          // boundary reg-part tables [K-1][sigma][j]
    __shared__ float2 CHiS[2][16];            // boundary thread-part, high nibble
    __shared__ float2 CLoS[2][2][16];         // boundary thread-part, low nibble
    __shared__ float red[4];
    float4* a4 = reinterpret_cast<float4*>(amp);

    const int tid = threadIdx.x;
    const int b = blockIdx.x;

    // ---- fused gate build + P*Ry(b)*Q decomposition ----
    const float xv = x[b];
    const float x1 = asinf(xv);
    const float x2 = acosf(xv * xv);
    const float cy = cosf(0.5f * x1), sy = sinf(0.5f * x1);
    const float cz = cosf(0.5f * x2), sz = sinf(0.5f * x2);
    const c32 M00 = {  cz * cy, -sz * cy };
    const c32 M01 = { -cz * sy,  sz * sy };
    const c32 M10 = {  cz * sy,  sz * sy };
    const c32 M11 = {  cz * cy,  sz * cy };

    if (tid < 4 * NQ) {
        const float* th = thetas + tid * 3;
        const float h0 = 0.5f * th[0], h1 = 0.5f * th[1], h2 = 0.5f * th[2];
        const float c0 = cosf(h0), s0 = sinf(h0);
        const float c1 = cosf(h1), s1 = sinf(h1);
        const float c2 = cosf(h2), s2 = sinf(h2);
        const c32 z0 = { c1, -s1 }, z1 = { c1, s1 };
        const c32 X00 = { c0, 0.f }, X01 = { 0.f, -s0 };
        const c32 A00 = cmul(z0, X00), A01 = cmul(z0, X01);
        const c32 A10 = cmul(z1, X01), A11 = cmul(z1, X00);
        const c32 Y00 = { c2, 0.f }, Y01 = { 0.f, -s2 };
        const c32 U00 = { Y00.r*A00.r - Y00.i*A00.i + Y01.r*A10.r - Y01.i*A10.i,
                          Y00.r*A00.i + Y00.i*A00.r + Y01.r*A10.i + Y01.i*A10.r };
        const c32 U01 = { Y00.r*A01.r - Y00.i*A01.i + Y01.r*A11.r - Y01.i*A11.i,
                          Y00.r*A01.i + Y00.i*A01.r + Y01.r*A11.i + Y01.i*A11.r };
        const c32 U10 = { Y01.r*A00.r - Y01.i*A00.i + Y00.r*A10.r - Y00.i*A10.i,
                          Y01.r*A00.i + Y01.i*A00.r + Y00.r*A10.i + Y00.i*A10.r };
        const c32 U11 = { Y01.r*A01.r - Y01.i*A01.i + Y00.r*A11.r - Y00.i*A11.i,
                          Y01.r*A01.i + Y01.i*A01.r + Y00.r*A11.i + Y00.i*A11.r };
        const c32 V00 = { U00.r*M00.r - U00.i*M00.i + U01.r*M10.r - U01.i*M10.i,
                          U00.r*M00.i + U00.i*M00.r + U01.r*M10.i + U01.i*M10.r };
        const c32 V01 = { U00.r*M01.r - U00.i*M01.i + U01.r*M11.r - U01.i*M11.i,
                          U00.r*M01.i + U00.i*M01.r + U01.r*M11.i + U01.i*M11.r };
        const c32 V10 = { U10.r*M00.r - U10.i*M00.i + U11.r*M10.r - U11.i*M10.i,
                          U10.r*M00.i + U10.i*M00.r + U11.r*M10.i + U11.i*M10.r };
        const c32 V11 = { U10.r*M01.r - U10.i*M01.i + U11.r*M11.r - U11.i*M11.i,
                          U10.r*M01.i + U10.i*M01.r + U11.r*M11.i + U11.i*M11.r };

        float cb = sqrtf(V00.r*V00.r + V00.i*V00.i);
        float sb = sqrtf(V10.r*V10.r + V10.i*V10.i);
        c32 p0, p1, q1;
        const float eps = 1e-6f;
        if (sb <= eps) {
            const float icb = 1.f / cb;
            p0 = { V00.r*icb, V00.i*icb };
            p1 = { V11.r*icb, V11.i*icb };
            q1 = { 1.f, 0.f };
            cb = 1.f; sb = 0.f;
        } else if (cb <= eps) {
            const float isb = 1.f / sb;
            p1 = { V10.r*isb, V10.i*isb };
            p0 = { -V01.r*isb, -V01.i*isb };
            q1 = { 1.f, 0.f };
            cb = 0.f; sb = 1.f;
        } else {
            const float icb = 1.f / cb, isb = 1.f / sb;
            p0 = { V00.r*icb, V00.i*icb };
            p1 = { V10.r*isb, V10.i*isb };
            const c32 t = { V11.r*p1.r + V11.i*p1.i, V11.i*p1.r - V11.r*p1.i };
            q1 = { t.r*icb, t.i*icb };
        }
        Vs[tid * 2]     = make_float4(cb, sb, p0.r, p0.i);
        Vs[tid * 2 + 1] = make_float4(p1.r, p1.i, q1.r, q1.i);
    }
    __syncthreads();

    // ---- boundary diag tables (K=1,2): B_K = P(K) * (Q(K+1) o gamma^{-1}) ----
    if (tid < 64) {
        const int bK = (tid >> 5) + 1;
        const int sg = (tid >> 4) & 1;
        const int j  = tid & 15;
        c32 acc = { 1.f, 0.f };
        #pragma unroll
        for (int m = 3; m >= 0; --m) {
            const int Q = 11 - m;
            const float4 s0 = Vs[(bK*NQ+Q)*2];
            const float4 s1 = Vs[(bK*NQ+Q)*2+1];
            const float4 n1 = Vs[((bK+1)*NQ+Q)*2+1];
            const c32 pf = ((j >> m) & 1) ? c32{ s1.x, s1.y } : c32{ s0.z, s0.w };
            acc = cmul(acc, pf);
            if (sg ^ (__popc(j >> m) & 1)) acc = cmul(acc, c32{ n1.z, n1.w });
        }
        TbS[bK-1][sg][j] = make_float2(acc.r, acc.i);
    } else if (tid < 96) {
        const int idx = tid - 64;
        const int bK = (idx >> 4) + 1;
        const int h  = idx & 15;
        c32 acc = { 1.f, 0.f };
        #pragma unroll
        for (int Q = 0; Q < 4; ++Q) {
            const float4 s0 = Vs[(bK*NQ+Q)*2];
            const float4 s1 = Vs[(bK*NQ+Q)*2+1];
            const float4 n1 = Vs[((bK+1)*NQ+Q)*2+1];
            const c32 pf = ((h >> (3-Q)) & 1) ? c32{ s1.x, s1.y } : c32{ s0.z, s0.w };
            acc = cmul(acc, pf);
            if (__popc(h >> (3-Q)) & 1) acc = cmul(acc, c32{ n1.z, n1.w });
        }
        CHiS[bK-1][h] = make_float2(acc.r, acc.i);
    } else if (tid < 160) {
        const int idx = tid - 96;
        const int bK = (idx >> 5) + 1;
        const int sh = (idx >> 4) & 1;
        const int lo = idx & 15;
        c32 acc = { 1.f, 0.f };
        #pragma unroll
        for (int Q = 4; Q < 8; ++Q) {
            const float4 s0 = Vs[(bK*NQ+Q)*2];
            const float4 s1 = Vs[(bK*NQ+Q)*2+1];
            const float4 n1 = Vs[((bK+1)*NQ+Q)*2+1];
            const c32 pf = ((lo >> (7-Q)) & 1) ? c32{ s1.x, s1.y } : c32{ s0.z, s0.w };
            acc = cmul(acc, pf);
            if (sh ^ (__popc(lo >> (7-Q)) & 1)) acc = cmul(acc, c32{ n1.z, n1.w });
        }
        CLoS[bK-1][sh][lo] = make_float2(acc.r, acc.i);
    }

    // ---- layer 0: tensor product (col-0 factors) with Q(1) folded in ----
    {
        const int sg0 = __popc(tid) & 1;
        c32 C = { 1.f, 0.f };
        #pragma unroll
        for (int q = 0; q < 8; ++q) {
            const float4 s0 = Vs[q*2];
            const float4 s1 = Vs[q*2+1];
            const bool bit = (tid >> (7 - q)) & 1;
            const c32 e = bit ? c32{ s1.x * s0.y, s1.y * s0.y }
                             : c32{ s0.z * s0.x, s0.w * s0.x };
            C = cmul(C, e);
            const float4 n1 = Vs[(NQ+q)*2+1];
            if (__popc(tid >> (7 - q)) & 1) C = cmul(C, c32{ n1.z, n1.w });
        }
        c32 pf0[4], pf1[4], qv[4];
        #pragma unroll
        for (int m = 0; m < 4; ++m) {
            const int Q = 11 - m;
            const float4 s0 = Vs[Q*2];
            const float4 s1 = Vs[Q*2+1];
            const float4 n1 = Vs[(NQ+Q)*2+1];
            pf0[m] = { s0.z * s0.x, s0.w * s0.x };
            pf1[m] = { s1.x * s0.y, s1.y * s0.y };
            qv[m]  = { n1.z, n1.w };
        }
        c32 T[16];
        diagTree(T, C, pf0, pf1, qv, sg0);
        const int beta = Cm(tid << 4);
        #pragma unroll
        for (int m = 0; m < 8; ++m)
            a4[(beta ^ (2 * m)) >> 1] =
                make_float4(T[2*m].r, T[2*m].i, T[2*m+1].r, T[2*m+1].i);
    }
    __syncthreads();

    // ---- layers 1..3: RY passes; pass1->pass2 boundary is intra-wave (no barrier);
    //      boundary diag at pass 2; layer-3 pass 2 fuses the readout ----
    const int Lo = tid & 15, Hh = tid >> 4;
    float acc = 0.f;

    #define RUN_LAYER(K)                                                            \
    {                                                                               \
        /* pass 0: qubits 0-3 (t bits 11-8) — cross-thread, full barrier after */   \
        {                                                                           \
            const float4 g0 = Vs[(K*NQ+0)*2], g1 = Vs[(K*NQ+1)*2];                  \
            const float4 g2 = Vs[(K*NQ+2)*2], g3 = Vs[(K*NQ+3)*2];                  \
            const int beta = Cm(G(tid, K));                                         \
            c32 v[16];                                                              \
            _Pragma("unroll")                                                       \
            for (int j = 0; j < 16; ++j) {                                          \
                const float2 t = amp[beta ^ Cm(G(j << 8, K))];                      \
                v[j] = { t.x, t.y };                                                \
            }                                                                       \
            applyRY<3>(v, g0.x, g0.y); applyRY<2>(v, g1.x, g1.y);                   \
            applyRY<1>(v, g2.x, g2.y); applyRY<0>(v, g3.x, g3.y);                   \
            _Pragma("unroll")                                                       \
            for (int j = 0; j < 16; ++j)                                            \
                amp[beta ^ Cm(G(j << 8, K))] = make_float2(v[j].r, v[j].i);         \
            __syncthreads();                                                        \
        }                                                                           \
        /* pass 1: qubits 4-7 (t bits 7-4) — exchange with pass 2 is intra-wave */  \
        {                                                                           \
            const float4 g0 = Vs[(K*NQ+4)*2], g1 = Vs[(K*NQ+5)*2];                  \
            const float4 g2 = Vs[(K*NQ+6)*2], g3 = Vs[(K*NQ+7)*2];                  \
            const int beta = Cm(G((Hh << 8) | Lo, K));                              \
            c32 v[16];                                                              \
            _Pragma("unroll")                                                       \
            for (int j = 0; j < 16; ++j) {                                          \
                const float2 t = amp[beta ^ Cm(G(j << 4, K))];                      \
                v[j] = { t.x, t.y };                                                \
            }                                                                       \
            applyRY<3>(v, g0.x, g0.y); applyRY<2>(v, g1.x, g1.y);                   \
            applyRY<1>(v, g2.x, g2.y); applyRY<0>(v, g3.x, g3.y);                   \
            _Pragma("unroll")                                                       \
            for (int j = 0; j < 16; ++j)                                            \
                amp[beta ^ Cm(G(j << 4, K))] = make_float2(v[j].r, v[j].i);         \
            wave_lds_fence();   /* same quarter-wave rereads: no s_barrier needed */ \
        }                                                                           \
        /* pass 2: qubits 8-11 (t bits 3-0), b128 reads */                          \
        {                                                                           \
            const float4 g0 = Vs[(K*NQ+8)*2],  g1 = Vs[(K*NQ+9)*2];                 \
            const float4 g2 = Vs[(K*NQ+10)*2], g3 = Vs[(K*NQ+11)*2];                \
            const int beta = Cm(G((Hh << 8) | (Lo << 4), K));                       \
            c32 v[16];                                                              \
            _Pragma("unroll")                                                       \
            for (int m = 0; m < 8; ++m) {                                           \
                const int gg = Cm(G(2 * m, K));                                     \
                const float4 F = a4[(beta ^ (gg & ~1)) >> 1];                       \
                const c32 flo = { F.x, F.y }, fhi = { F.z, F.w };                   \
                if (gg & 1) { v[2*m+1] = flo; v[2*m] = fhi; }                       \
                else        { v[2*m] = flo;   v[2*m+1] = fhi; }                     \
            }                                                                       \
            applyRY<3>(v, g0.x, g0.y); applyRY<2>(v, g1.x, g1.y);                   \
            applyRY<1>(v, g2.x, g2.y); applyRY<0>(v, g3.x, g3.y);                   \
            if constexpr (K < 3) {                                                  \
                const int sgm = __popc(tid) & 1;                                    \
                const int sgh = __popc(tid >> 4) & 1;                               \
                const float2 ch = CHiS[K-1][Hh];                                    \
                const float2 cl = CLoS[K-1][sgh][Lo];                               \
                const c32 CT = cmul(c32{ch.x,ch.y}, c32{cl.x,cl.y});                \
                _Pragma("unroll")                                                   \
                for (int j = 0; j < 16; ++j) {                                      \
                    const float2 tb = TbS[K-1][sgm][j];                             \
                    v[j] = cmul(v[j], cmul(CT, c32{tb.x, tb.y}));                   \
                }                                                                   \
                _Pragma("unroll")                                                   \
                for (int m = 0; m < 8; ++m) {                                       \
                    const int gg = Cm(G(2 * m, K));                                 \
                    float4 F;                                                       \
                    if (gg & 1) F = make_float4(v[2*m+1].r, v[2*m+1].i, v[2*m].r,   v[2*m].i); \
                    else        F = make_float4(v[2*m].r,   v[2*m].i,   v[2*m+1].r, v[2*m+1].i); \
                    a4[(beta ^ (gg & ~1)) >> 1] = F;                                \
                }                                                                   \
                __syncthreads();                                                    \
            } else {                                                                \
                /* fused readout: t = (Hh<<8)|(Lo<<4)|j, weight = parity(t&0x555) */ \
                const int sgnHL = (__popc(Hh & 5) ^ __popc(Lo & 5)) & 1;            \
                _Pragma("unroll")                                                   \
                for (int j = 0; j < 16; ++j) {                                      \
                    const float m2 = fmaf(v[j].r, v[j].r, v[j].i * v[j].i);         \
                    acc += ((sgnHL ^ __popc(j & 5)) & 1) ? -m2 : m2;                \
                }                                                                   \
            }                                                                       \
        }                                                                           \
    }

    RUN_LAYER(1)
    RUN_LAYER(2)
    RUN_LAYER(3)
    #undef RUN_LAYER

    // ---- reduce 256 threads ----
    #pragma unroll
    for (int off = 32; off > 0; off >>= 1) acc += __shfl_down(acc, off, 64);
    if ((tid & 63) == 0) red[tid >> 6] = acc;
    __syncthreads();
    if (tid == 0) out[b] = red[0] + red[1] + red[2] + red[3];
}

} // namespace

extern "C" void kernel_launch(void* const* d_in, const int* in_sizes, int n_in,
                              void* d_out, int out_size, void* d_ws, size_t ws_size,
                              hipStream_t stream) {
    const float* x      = (const float*)d_in[0];
    const float* thetas = (const float*)d_in[1];
    float* out          = (float*)d_out;
    const int batch = in_sizes[0];
    qcirc_kernel<<<batch, THREADS, 0, stream>>>(x, thetas, out);
}